// Round 20
// baseline (99.359 us; speedup 1.0000x reference)
//
#include <hip/hip_runtime.h>

#define N_ 4
#define L_ 1024
#define H_ 8
#define D_ 64

typedef _Float16 f16x8 __attribute__((ext_vector_type(8)));
typedef _Float16 f16x4 __attribute__((ext_vector_type(4)));
typedef _Float16 f16x2 __attribute__((ext_vector_type(2)));
typedef float f32x4 __attribute__((ext_vector_type(4)));

#define MFMA(A, B, C) __builtin_amdgcn_mfma_f32_16x16x32_f16(A, B, C, 0, 0, 0)
#define EXP2(x) __builtin_amdgcn_exp2f(x)

__device__ __forceinline__ ushort f2h(float x) {
    union { _Float16 h; ushort u; } c;
    c.h = (_Float16)x;
    return c.u;
}
__device__ __forceinline__ f16x8 ld8(const ushort* p) {
    return *(const f16x8*)p;
}
__device__ __forceinline__ f16x4 pack4(float a, float b, float c, float d) {
    union { f16x4 v; f16x2 h[2]; } u;
    u.h[0] = __builtin_bit_cast(f16x2, __builtin_amdgcn_cvt_pkrtz(a, b));
    u.h[1] = __builtin_bit_cast(f16x2, __builtin_amdgcn_cvt_pkrtz(c, d));
    return u.v;
}
__device__ __forceinline__ f16x8 negf(f16x8 a) {
    uint4 u = __builtin_bit_cast(uint4, a);
    u.x ^= 0x80008000u; u.y ^= 0x80008000u; u.z ^= 0x80008000u; u.w ^= 0x80008000u;
    return __builtin_bit_cast(f16x8, u);
}
// load 8 consecutive f32, scale by s, convert to f16x8
__device__ __forceinline__ f16x8 cvt8s(const float* p, float s) {
    float4 a = *(const float4*)p;
    float4 b = *(const float4*)(p + 4);
    union { f16x8 v; _Float16 e[8]; } u;
    u.e[0] = (_Float16)(a.x * s); u.e[1] = (_Float16)(a.y * s);
    u.e[2] = (_Float16)(a.z * s); u.e[3] = (_Float16)(a.w * s);
    u.e[4] = (_Float16)(b.x * s); u.e[5] = (_Float16)(b.y * s);
    u.e[6] = (_Float16)(b.z * s); u.e[7] = (_Float16)(b.w * s);
    return u.v;
}
#define SCQ 0.18033688011112f   // (1/8)*log2(e)
__device__ __forceinline__ f16x8 cvt8(const float* p) { return cvt8s(p, SCQ); }

// async global -> LDS, 16B per lane, wave-uniform LDS base + lane*16
__device__ __forceinline__ void gl_lds16(const ushort* g, ushort* l) {
    __builtin_amdgcn_global_load_lds(
        (const __attribute__((address_space(1))) unsigned int*)g,
        (__attribute__((address_space(3))) unsigned int*)l, 16, 0, 0);
}

// ---- convert K: fp32 [n][l][h][d] -> f16 [aid][n][h][l][d], aid in {kr,ki}
__global__ void cvt_k(const float* __restrict__ k_r, const float* __restrict__ k_i,
                      ushort* __restrict__ dst) {
    int gid = blockIdx.x * 256 + threadIdx.x;   // 0..1048575 (x4 elems each)
    int aid = gid >> 19;
    int idx = (gid & 0x7FFFF) << 2;             // flat [n][h][l][d]
    int d  = idx & 63;
    int l  = (idx >> 6) & 1023;
    int hh = (idx >> 16) & 7;
    int n  = idx >> 19;
    const float* src = aid ? k_i : k_r;
    const float4 v = *(const float4*)(src + (((long)n * 1024 + l) * 8 + hh) * 64 + d);
    ushort4 o = make_ushort4(f2h(v.x), f2h(v.y), f2h(v.z), f2h(v.w));
    *(ushort4*)(dst + ((long)aid << 21) + idx) = o;
}

// ---- convert V: fp32 [n][s][h][d] -> f16 transposed+s-permuted
//      [aid][n][h][d][s'] with s' = c*32 + g*8 + sb*4 + e  (s = c*32+sb*16+g*4+e)
__global__ void cvt_v(const float* __restrict__ vr, const float* __restrict__ vi,
                      ushort* __restrict__ dst) {
    __shared__ ushort t[64][72];
    int bid = blockIdx.x;
    int aid = bid >> 9;
    int b   = bid & 511;
    int s0  = (b & 15) << 6;
    int hh  = (b >> 4) & 7;
    int n   = b >> 7;
    const float* src = aid ? vi : vr;
    int tid = threadIdx.x;
    int r  = tid >> 4;
    int cq = (tid & 15) << 2;
#pragma unroll
    for (int it = 0; it < 4; ++it) {
        int s = s0 + it * 16 + r;
        const float4 v = *(const float4*)(src + (((long)n * 1024 + s) * 8 + hh) * 64 + cq);
        t[it * 16 + r][cq + 0] = f2h(v.x);
        t[it * 16 + r][cq + 1] = f2h(v.y);
        t[it * 16 + r][cq + 2] = f2h(v.z);
        t[it * 16 + r][cq + 3] = f2h(v.w);
    }
    __syncthreads();
    // s-permute within each 32-chunk: noff = (cq&32) + g*8 + sb*4
    const int rem = cq & 31;
    const int noff = (cq & 32) + (((rem & 15) >> 2) << 3) + ((rem >> 4) << 2);
#pragma unroll
    for (int it = 0; it < 4; ++it) {
        int dd = it * 16 + r;
        ushort4 o;
        o.x = t[cq + 0][dd]; o.y = t[cq + 1][dd]; o.z = t[cq + 2][dd]; o.w = t[cq + 3][dd];
        *(ushort4*)(dst + ((long)aid << 21) + (((long)n * 8 + hh) * 64 + dd) * 1024 + s0 + noff) = o;
    }
}

// ws element layout (ushort): Kr @0, Ki @1<<21, Vr' @2<<21, Vi' @3<<21 (16 MB)
// rdbuf (float): byte offset 16 MB; [0,32768) = rdR (p=0), [32768,65536) = rdI.

// ---- flash-style single-pass attention, PARITY-SPLIT + SWAPPED QK^T ----
// grid 512 (XCD-swizzled -> (nh, l-tile64)), block 512 = 8 waves (same nh):
// wave = (p parity, lsub); 16 rows x full 1024 s, one parity arg.
// Swapped scores: MFMA(K,Q) -> lane(col,g) reg r = w[l=col][s=sb*16+4g+r].
// [pw0|pw1] is EXACTLY the k=32 A-frag, V' permutation is its B-frag k-map
// -> PV = 8 MFMA32/chunk. 3-buffer staging + counted vmcnt(2) + raw s_barrier
// (T3/T4): staging loads stay in flight across barriers, no per-chunk drain.
__launch_bounds__(512, 4)
__global__ void attn_u(const float* __restrict__ qr_g, const float* __restrict__ qi_g,
                       const ushort* __restrict__ ws, float* __restrict__ rdbuf,
                       float* __restrict__ out) {
    __shared__ ushort stgK[3][4096];   // 24KB
    __shared__ ushort stgV[3][4096];   // 24KB

    const int tid  = threadIdx.x;
    const int lane = tid & 63;
    const int wv   = tid >> 6;
    const int p    = wv >> 2;       // parity
    const int lsub = wv & 3;        // l-subtile
    const int col  = lane & 15;
    const int g    = lane >> 4;

    // XCD swizzle: XCD x serves nh in [4x,4x+4) -> 2MB K+V slice per L2
    const int id = blockIdx.x;
    const int x  = id & 7;
    const int j  = id >> 3;              // 0..63
    const int nh = x * 4 + (j >> 4);
    const int n  = nh >> 3;
    const int h  = nh & 7;
    const int l0 = (j & 15) * 64 + lsub * 16;

    const ushort* Kr = ws + ((long)nh << 16);                 // [1024][64]
    const ushort* Ki = ws + (1l << 21) + ((long)nh << 16);
    const ushort* Vr = ws + (2l << 21) + ((long)nh << 16);    // [64][1024'] perm
    const ushort* Vi = ws + (3l << 21) + ((long)nh << 16);

    // Q fragments (row = col, k = g*8+e, +32); qx pre-signed: -qi for p=0
    const long qg = (((long)n * 1024 + l0 + col) * 8 + h) * 64 + g * 8;
    const float sgn = p ? SCQ : -SCQ;
    const f16x8 qr0 = cvt8(qr_g + qg), qr1 = cvt8(qr_g + qg + 32);
    const f16x8 qx0 = cvt8s(qi_g + qg, sgn), qx1 = cvt8s(qi_g + qg + 32, sgn);

    // ---- staging slots: thread tid stages one K 16B-block + one V 16B-block
    const int kpart = tid >> 8;
    const int ksr   = (tid >> 3) & 31;
    const int kbo   = (tid & 7) ^ (ksr & 7);        // source block (inv swizzle)
    const ushort* Ksrc = (kpart ? Ki : Kr);
    const int vd  = tid >> 3;
    const int vb  = (tid & 7) ^ (vd & 7);
    const ushort* Vsrc = ((vb >> 2) ? Vi : Vr);
    const int vbo = (vb & 3) * 8;
    ushort* kbase = &stgK[0][0] + wv * 512;
    ushort* vbase = &stgV[0][0] + wv * 512;

    float dsum = 0.f;
    f32x4 uA[4], uB[4];
#pragma unroll
    for (int db = 0; db < 4; ++db) {
        uA[db] = (f32x4){0.f, 0.f, 0.f, 0.f};
        uB[db] = (f32x4){0.f, 0.f, 0.f, 0.f};
    }

    // read-side swizzled offsets (lane-constant, ^(row&7) over 8 blocks)
    const int kx  = (g ^ (col & 7)) * 8;         // K A-frag k=g*8+e
    const int kx2 = ((g + 4) ^ (col & 7)) * 8;   //        k=32+g*8+e
    const int vxA = (g ^ (col & 7)) * 8;         // V part0 (blk g)
    const int vxB = ((4 + g) ^ (col & 7)) * 8;   // V part1 (blk 4+g)

#define STAGE(bb, cc)                                                        \
    do {                                                                     \
        gl_lds16(Ksrc + (long)((cc) * 32 + ksr) * 64 + kbo * 8,              \
                 kbase + (bb) * 4096);                                       \
        gl_lds16(Vsrc + (long)vd * 1024 + (cc) * 32 + vbo,                   \
                 vbase + (bb) * 4096);                                       \
    } while (0)

    STAGE(0, 0);
    STAGE(1, 1);
    asm volatile("s_waitcnt vmcnt(2)" ::: "memory");   // buf0 complete
    __builtin_amdgcn_s_barrier();

    int bc = 0;
    for (int cc = 0; cc < 32; ++cc) {
        if (cc < 30) {
            const int bp = (cc + 2 >= 3) ? (cc + 2) % 3 : cc + 2;
            STAGE(bp, cc + 2);
        }
        const ushort* sk = &stgK[0][0] + bc * 4096;
        const ushort* sv = &stgV[0][0] + bc * 4096;

        // ---- swapped one-parity QK^T: C = S^T, exp2 + pack in-register ----
        union { f16x8 w8; f16x4 q[2]; } pw;
#pragma unroll
        for (int sb = 0; sb < 2; ++sb) {
            const int rb = (sb * 16 + col) * 64;
            f16x8 ka0 = ld8(&sk[p * 2048 + rb + kx]);
            f16x8 ka1 = ld8(&sk[p * 2048 + rb + kx2]);
            f16x8 kb0 = ld8(&sk[(p ^ 1) * 2048 + rb + kx]);
            f16x8 kb1 = ld8(&sk[(p ^ 1) * 2048 + rb + kx2]);
            f32x4 a0 = (f32x4){0.f, 0.f, 0.f, 0.f};
            a0 = MFMA(ka0, qr0, a0); a0 = MFMA(ka1, qr1, a0);
            a0 = MFMA(kb0, qx0, a0); a0 = MFMA(kb1, qx1, a0);
            const float w0 = EXP2(a0[0]), w1 = EXP2(a0[1]);
            const float w2 = EXP2(a0[2]), w3 = EXP2(a0[3]);
            dsum += (w0 + w1) + (w2 + w3);
            pw.q[sb] = pack4(w0, w1, w2, w3);
        }

        // ---- PV: one b128 + one MFMA32 per (db, part) ----
        __builtin_amdgcn_s_setprio(1);
#pragma unroll
        for (int db = 0; db < 4; ++db) {
            const int rv = (db * 16 + col) * 64;
            uA[db] = MFMA(pw.w8, ld8(&sv[rv + vxA]), uA[db]);
            uB[db] = MFMA(pw.w8, ld8(&sv[rv + vxB]), uB[db]);
        }
        __builtin_amdgcn_s_setprio(0);

        if (cc < 31) {
            if (cc < 30) asm volatile("s_waitcnt vmcnt(2)" ::: "memory");
            else         asm volatile("s_waitcnt vmcnt(0)" ::: "memory");
            __builtin_amdgcn_s_barrier();
        }
        bc = (bc == 2) ? 0 : bc + 1;
    }

    // ---- denominator: lane holds partial for l=col; reduce over g-lanes ----
    dsum += __shfl_xor(dsum, 16);
    dsum += __shfl_xor(dsum, 32);
    const float rd = 1.f / dsum;
    if (lane < 16) rdbuf[p * 32768 + nh * 1024 + l0 + col] = rd;

    // u rows are l=4g+r -> fetch rd from lane 4g+r
    float rdl[4];
#pragma unroll
    for (int r = 0; r < 4; ++r) rdl[r] = __shfl(rd, 4 * g + r);

#pragma unroll
    for (int db = 0; db < 4; ++db) {
#pragma unroll
        for (int r = 0; r < 4; ++r) {
            uA[db][r] *= rdl[r];
            uB[db][r] *= rdl[r];
        }
    }

    // ---- exchange via dead stgK (24KB): [lsub][lane][16 f32] contiguous ----
    __syncthreads();   // all main-loop LDS reads complete before aliasing
    float* cb = (float*)&stgK[0][0];
    const int ci = (lsub * 64 + lane) * 16;
    if (p == 1) {
#pragma unroll
        for (int db = 0; db < 4; ++db) *(f32x4*)&cb[ci + db * 4] = uB[db];
    }
    __syncthreads();
    f32x4 oR[4];
    if (p == 0) {
#pragma unroll
        for (int db = 0; db < 4; ++db) oR[db] = uA[db] - *(f32x4*)&cb[ci + db * 4];
    }
    __syncthreads();
    if (p == 1) {
#pragma unroll
        for (int db = 0; db < 4; ++db) *(f32x4*)&cb[ci + db * 4] = uA[db];
    }
    __syncthreads();

    if (p == 0) {
        const long OFF_UI = 2097152;
#pragma unroll
        for (int db = 0; db < 4; ++db) {
            f32x4 oI = uB[db] + *(f32x4*)&cb[ci + db * 4];
#pragma unroll
            for (int r = 0; r < 4; ++r) {
                const int l = l0 + 4 * g + r;
                const int d = db * 16 + col;
                const long base = (((long)n * L_ + l) * H_ + h) * D_ + d;
                out[base] = oR[db][r];
                out[OFF_UI + base] = oI[r];
            }
        }
    }
#undef STAGE
}

// ---- a = 0.125 * sum_h exp2(arg_h) * rd_h ---- LDS-staged K recompute
// grid 1024 (XCD-swizzled -> (n, l-tile64, s-chunk64)), block 256 = 4 waves,
// wave owns 16 l-rows x full 64-s chunk. h-loop with double-buffered LDS K
// staging (global_load_lds, both-sides XOR swizzle), in-register h-sum.
__launch_bounds__(256, 4)
__global__ void kern_a(const float* __restrict__ qr_g, const float* __restrict__ qi_g,
                      const ushort* __restrict__ ws, const float* __restrict__ rdbuf,
                      float* __restrict__ out) {
    __shared__ ushort stgK[2][2][64][64];   // [buf][part][s][d]  32KB
    __shared__ float lrd[8][2][64];         // [h][part][row]      4KB

    const int tid  = threadIdx.x;
    const int lane = tid & 63;
    const int wv   = tid >> 6;
    const int col  = lane & 15;
    const int g    = lane >> 4;

    // XCD swizzle: id&7 = XCD x; n = x>>1 -> K(n)=4MB resident per L2 pair
    const int id  = blockIdx.x;
    const int x   = id & 7;
    const int q   = id >> 3;             // 0..127
    const int n   = x >> 1;
    const int idx = (x & 1) * 128 + q;   // 0..255 within n
    const int lt0 = (idx >> 4) * 64;     // l-tile base
    const int sc  = idx & 15;            // s-chunk (64 cols)
    const int l0  = lt0 + wv * 16;       // wave's row base

    const ushort* KrB = ws + ((long)(n * 8) << 16);             // head 0
    const ushort* KiB = ws + (1l << 21) + ((long)(n * 8) << 16);

    // preload rd for all 8 heads x 64 rows
#pragma unroll
    for (int i = 0; i < 4; ++i) {
        const int t = i * 256 + tid;
        (&lrd[0][0][0])[t] =
            rdbuf[((t >> 6) & 1) * 32768 + (n * 8 + (t >> 7)) * 1024 + lt0 + (t & 63)];
    }

    // staging roles: wave stages part sp, rows (wv&1)*32 .. +32
    const int sp   = wv >> 1;
    const int kbs  = ((lane & 7) ^ (lane >> 3)) * 8;   // pre-swizzled src block

#define STAGEA(buf, hh)                                                      \
    do {                                                                     \
        const ushort* Kp = (sp ? KiB : KrB) + ((long)(hh) << 16);            \
        _Pragma("unroll")                                                    \
        for (int i = 0; i < 4; ++i) {                                        \
            const int krow = (wv & 1) * 32 + i * 8 + (lane >> 3);            \
            gl_lds16(Kp + (long)(sc * 64 + krow) * 64 + kbs,                 \
                     &stgK[buf][sp][(wv & 1) * 32 + i * 8][0]);              \
        }                                                                    \
    } while (0)

    f32x4 aR[4], aI[4];
#pragma unroll
    for (int i = 0; i < 4; ++i) {
        aR[i] = (f32x4){0.f, 0.f, 0.f, 0.f};
        aI[i] = (f32x4){0.f, 0.f, 0.f, 0.f};
    }

    const int kx  = (g ^ (col & 7)) * 8;
    const int kx2 = ((g + 4) ^ (col & 7)) * 8;

    STAGEA(0, 0);
    __syncthreads();

    for (int h = 0; h < 8; ++h) {
        const int buf = h & 1;
        if (h < 7) STAGEA(buf ^ 1, h + 1);

        // Q fragments for this head (row = col of wave's 16, k = g*8+e)
        const long qg = (((long)n * 1024 + l0 + col) * 8 + h) * 64 + g * 8;
        const f16x8 qr0 = cvt8(qr_g + qg), qr1 = cvt8(qr_g + qg + 32);
        const f16x8 qi0 = cvt8(qi_g + qg), qi1 = cvt8(qi_g + qg + 32);
        const f16x8 qn0 = negf(qi0), qn1 = negf(qi1);

        float rdR[4], rdI[4];
#pragma unroll
        for (int r = 0; r < 4; ++r) {
            rdR[r] = lrd[h][0][wv * 16 + 4 * g + r];
            rdI[r] = lrd[h][1][wv * 16 + 4 * g + r];
        }

#pragma unroll
        for (int sb = 0; sb < 4; ++sb) {
            const int row = sb * 16 + col;
            f16x8 kr0 = ld8(&stgK[buf][0][row][kx]);
            f16x8 kr1 = ld8(&stgK[buf][0][row][kx2]);
            f16x8 ki0 = ld8(&stgK[buf][1][row][kx]);
            f16x8 ki1 = ld8(&stgK[buf][1][row][kx2]);
            f32x4 a0 = (f32x4){0.f, 0.f, 0.f, 0.f};
            a0 = MFMA(qr0, kr0, a0); a0 = MFMA(qr1, kr1, a0);
            a0 = MFMA(qn0, ki0, a0); a0 = MFMA(qn1, ki1, a0);
            f32x4 a1 = (f32x4){0.f, 0.f, 0.f, 0.f};
            a1 = MFMA(qr0, ki0, a1); a1 = MFMA(qr1, ki1, a1);
            a1 = MFMA(qi0, kr0, a1); a1 = MFMA(qi1, kr1, a1);
#pragma unroll
            for (int r = 0; r < 4; ++r) {
                aR[sb][r] += EXP2(a0[r]) * rdR[r];
                aI[sb][r] += EXP2(a1[r]) * rdI[r];
            }
        }
        __syncthreads();
    }

    const long OFF_AR = 4194304;
    const long OFF_AI = 8388608;
#pragma unroll
    for (int sb = 0; sb < 4; ++sb) {
#pragma unroll
        for (int r = 0; r < 4; ++r) {
            const int l = l0 + 4 * g + r;
            const int s = sc * 64 + sb * 16 + col;
            const long ab = ((long)n * 1024 + l) * 1024 + s;
            out[OFF_AR + ab] = aR[sb][r] * 0.125f;
            out[OFF_AI + ab] = aI[sb][r] * 0.125f;
        }
    }
#undef STAGEA
}

extern "C" void kernel_launch(void* const* d_in, const int* in_sizes, int n_in,
                              void* d_out, int out_size, void* d_ws, size_t ws_size,
                              hipStream_t stream) {
    const float* qr = (const float*)d_in[0];
    const float* qi = (const float*)d_in[1];
    const float* kr = (const float*)d_in[2];
    const float* ki = (const float*)d_in[3];
    const float* vr = (const float*)d_in[4];
    const float* vi = (const float*)d_in[5];
    ushort* ws = (ushort*)d_ws;                              // 16 MB f16 K/V
    float* rdbuf = (float*)((char*)d_ws + (16ull << 20));    // 256 KB @ 16 MB
    float* out = (float*)d_out;

    hipLaunchKernelGGL(cvt_k, dim3(4096), dim3(256), 0, stream, kr, ki, ws);
    hipLaunchKernelGGL(cvt_v, dim3(1024), dim3(256), 0, stream, vr, vi, ws + (2l << 21));
    hipLaunchKernelGGL(attn_u, dim3(512), dim3(512), 0, stream, qr, qi, ws, rdbuf, out);
    hipLaunchKernelGGL(kern_a, dim3(1024), dim3(256), 0, stream, qr, qi, ws, rdbuf, out);
}

// Round 21
// 94.335 us; speedup vs baseline: 1.0533x; 1.0533x over previous
//
#include <hip/hip_runtime.h>

#define N_ 4
#define L_ 1024
#define H_ 8
#define D_ 64

typedef _Float16 f16x8 __attribute__((ext_vector_type(8)));
typedef _Float16 f16x4 __attribute__((ext_vector_type(4)));
typedef _Float16 f16x2 __attribute__((ext_vector_type(2)));
typedef float f32x4 __attribute__((ext_vector_type(4)));

#define MFMA(A, B, C) __builtin_amdgcn_mfma_f32_16x16x32_f16(A, B, C, 0, 0, 0)
#define EXP2(x) __builtin_amdgcn_exp2f(x)

__device__ __forceinline__ ushort f2h(float x) {
    union { _Float16 h; ushort u; } c;
    c.h = (_Float16)x;
    return c.u;
}
__device__ __forceinline__ f16x8 ld8(const ushort* p) {
    return *(const f16x8*)p;
}
__device__ __forceinline__ f16x4 pack4(float a, float b, float c, float d) {
    union { f16x4 v; f16x2 h[2]; } u;
    u.h[0] = __builtin_bit_cast(f16x2, __builtin_amdgcn_cvt_pkrtz(a, b));
    u.h[1] = __builtin_bit_cast(f16x2, __builtin_amdgcn_cvt_pkrtz(c, d));
    return u.v;
}
__device__ __forceinline__ f16x8 negf(f16x8 a) {
    uint4 u = __builtin_bit_cast(uint4, a);
    u.x ^= 0x80008000u; u.y ^= 0x80008000u; u.z ^= 0x80008000u; u.w ^= 0x80008000u;
    return __builtin_bit_cast(f16x8, u);
}
// load 8 consecutive f32, scale by s, convert to f16x8
__device__ __forceinline__ f16x8 cvt8s(const float* p, float s) {
    float4 a = *(const float4*)p;
    float4 b = *(const float4*)(p + 4);
    union { f16x8 v; _Float16 e[8]; } u;
    u.e[0] = (_Float16)(a.x * s); u.e[1] = (_Float16)(a.y * s);
    u.e[2] = (_Float16)(a.z * s); u.e[3] = (_Float16)(a.w * s);
    u.e[4] = (_Float16)(b.x * s); u.e[5] = (_Float16)(b.y * s);
    u.e[6] = (_Float16)(b.z * s); u.e[7] = (_Float16)(b.w * s);
    return u.v;
}
#define SCQ 0.18033688011112f   // (1/8)*log2(e)
__device__ __forceinline__ f16x8 cvt8(const float* p) { return cvt8s(p, SCQ); }

// async global -> LDS, 16B per lane, wave-uniform LDS base + lane*16
__device__ __forceinline__ void gl_lds16(const ushort* g, ushort* l) {
    __builtin_amdgcn_global_load_lds(
        (const __attribute__((address_space(1))) unsigned int*)g,
        (__attribute__((address_space(3))) unsigned int*)l, 16, 0, 0);
}

// ---- merged conversion kernel ----
// blocks [0,4096): K fp32 [n][l][h][d] -> f16 [aid][n][h][l][d]
// blocks [4096,5120): V fp32 [n][s][h][d] -> f16 transposed+s-permuted
//      [aid][n][h][d][s'] with s' = c*32 + g*8 + sb*4 + e (s = c*32+sb*16+g*4+e)
__global__ void cvt_kv(const float* __restrict__ k_r, const float* __restrict__ k_i,
                       const float* __restrict__ vr, const float* __restrict__ vi,
                       ushort* __restrict__ dst) {
    __shared__ ushort t[64][72];
    const int tid = threadIdx.x;
    if (blockIdx.x < 4096) {
        int gid = blockIdx.x * 256 + tid;           // 0..1048575 (x4 elems each)
        int aid = gid >> 19;
        int idx = (gid & 0x7FFFF) << 2;             // flat [n][h][l][d]
        int d  = idx & 63;
        int l  = (idx >> 6) & 1023;
        int hh = (idx >> 16) & 7;
        int n  = idx >> 19;
        const float* src = aid ? k_i : k_r;
        const float4 v = *(const float4*)(src + (((long)n * 1024 + l) * 8 + hh) * 64 + d);
        ushort4 o = make_ushort4(f2h(v.x), f2h(v.y), f2h(v.z), f2h(v.w));
        *(ushort4*)(dst + ((long)aid << 21) + idx) = o;
        return;
    }
    int bid = blockIdx.x - 4096;
    int aid = bid >> 9;
    int b   = bid & 511;
    int s0  = (b & 15) << 6;
    int hh  = (b >> 4) & 7;
    int n   = b >> 7;
    const float* src = aid ? vi : vr;
    int r  = tid >> 4;
    int cq = (tid & 15) << 2;
#pragma unroll
    for (int it = 0; it < 4; ++it) {
        int s = s0 + it * 16 + r;
        const float4 v = *(const float4*)(src + (((long)n * 1024 + s) * 8 + hh) * 64 + cq);
        t[it * 16 + r][cq + 0] = f2h(v.x);
        t[it * 16 + r][cq + 1] = f2h(v.y);
        t[it * 16 + r][cq + 2] = f2h(v.z);
        t[it * 16 + r][cq + 3] = f2h(v.w);
    }
    __syncthreads();
    // s-permute within each 32-chunk: noff = (cq&32) + g*8 + sb*4
    const int rem = cq & 31;
    const int noff = (cq & 32) + (((rem & 15) >> 2) << 3) + ((rem >> 4) << 2);
#pragma unroll
    for (int it = 0; it < 4; ++it) {
        int dd = it * 16 + r;
        ushort4 o;
        o.x = t[cq + 0][dd]; o.y = t[cq + 1][dd]; o.z = t[cq + 2][dd]; o.w = t[cq + 3][dd];
        *(ushort4*)(dst + (2l << 21) + ((long)aid << 21) +
                    (((long)n * 8 + hh) * 64 + dd) * 1024 + s0 + noff) = o;
    }
}

// ws element layout (ushort): Kr @0, Ki @1<<21, Vr' @2<<21, Vi' @3<<21 (16 MB)
// rdbuf (float): byte offset 16 MB; [0,32768) = rdR (p=0), [32768,65536) = rdI.

// ---- flash-style single-pass attention, PARITY-SPLIT + SWAPPED QK^T ----
// grid 512 (XCD-swizzled -> (nh, l-tile64)), block 512 = 8 waves (same nh):
// wave = (p parity, lsub); 16 rows x full 1024 s, one parity arg.
// Swapped scores: MFMA(K,Q) -> lane(col,g) reg r = w[l=col][s=sb*16+4g+r].
// [pw0|pw1] is EXACTLY the k=32 A-frag (k=g*8+sb*4+r), and the V' permutation
// is exactly its B-frag k-map -> PV = 8 MFMA32/chunk.
__launch_bounds__(512, 4)
__global__ void attn_u(const float* __restrict__ qr_g, const float* __restrict__ qi_g,
                       const ushort* __restrict__ ws, float* __restrict__ rdbuf,
                       float* __restrict__ out) {
    __shared__ ushort stgK[2][4096];   // 16KB
    __shared__ ushort stgV[2][4096];   // 16KB

    const int tid  = threadIdx.x;
    const int lane = tid & 63;
    const int wv   = tid >> 6;
    const int p    = wv >> 2;       // parity
    const int lsub = wv & 3;        // l-subtile
    const int col  = lane & 15;
    const int g    = lane >> 4;

    // XCD swizzle: XCD x serves nh in [4x,4x+4) -> 2MB K+V slice per L2
    const int id = blockIdx.x;
    const int x  = id & 7;
    const int j  = id >> 3;              // 0..63
    const int nh = x * 4 + (j >> 4);
    const int n  = nh >> 3;
    const int h  = nh & 7;
    const int l0 = (j & 15) * 64 + lsub * 16;

    const ushort* Kr = ws + ((long)nh << 16);                 // [1024][64]
    const ushort* Ki = ws + (1l << 21) + ((long)nh << 16);
    const ushort* Vr = ws + (2l << 21) + ((long)nh << 16);    // [64][1024'] perm
    const ushort* Vi = ws + (3l << 21) + ((long)nh << 16);

    // Q fragments (row = col, k = g*8+e, +32); qx pre-signed: -qi for p=0
    const long qg = (((long)n * 1024 + l0 + col) * 8 + h) * 64 + g * 8;
    const float sgn = p ? SCQ : -SCQ;
    const f16x8 qr0 = cvt8(qr_g + qg), qr1 = cvt8(qr_g + qg + 32);
    const f16x8 qx0 = cvt8s(qi_g + qg, sgn), qx1 = cvt8s(qi_g + qg + 32, sgn);

    // ---- staging slots: thread tid stages one K 16B-block + one V 16B-block
    const int kpart = tid >> 8;
    const int ksr   = (tid >> 3) & 31;
    const int kbo   = (tid & 7) ^ (ksr & 7);        // source block (inv swizzle)
    const ushort* Ksrc = (kpart ? Ki : Kr);
    const int vd  = tid >> 3;
    const int vb  = (tid & 7) ^ (vd & 7);
    const ushort* Vsrc = ((vb >> 2) ? Vi : Vr);
    const int vbo = (vb & 3) * 8;
    ushort* kdst0 = &stgK[0][wv * 512];
    ushort* kdst1 = &stgK[1][wv * 512];
    ushort* vdst0 = &stgV[0][wv * 512];
    ushort* vdst1 = &stgV[1][wv * 512];

    float dsum = 0.f;
    f32x4 uA[4], uB[4];
#pragma unroll
    for (int db = 0; db < 4; ++db) {
        uA[db] = (f32x4){0.f, 0.f, 0.f, 0.f};
        uB[db] = (f32x4){0.f, 0.f, 0.f, 0.f};
    }

    // read-side swizzled offsets (lane-constant, ^(row&7) over 8 blocks)
    const int kx  = (g ^ (col & 7)) * 8;         // K A-frag k=g*8+e
    const int kx2 = ((g + 4) ^ (col & 7)) * 8;   //        k=32+g*8+e
    const int vxA = (g ^ (col & 7)) * 8;         // V part0 (blk g)
    const int vxB = ((4 + g) ^ (col & 7)) * 8;   // V part1 (blk 4+g)

#define STAGE(kd, vd_, cc)                                                   \
    do {                                                                     \
        gl_lds16(Ksrc + (long)((cc) * 32 + ksr) * 64 + kbo * 8, kd);         \
        gl_lds16(Vsrc + (long)vd * 1024 + (cc) * 32 + vbo, vd_);             \
    } while (0)

    STAGE(kdst0, vdst0, 0);
    __syncthreads();

    for (int cc = 0; cc < 32; ++cc) {
        const int buf = cc & 1;
        if (cc < 31) {
            if (buf) STAGE(kdst0, vdst0, cc + 1);
            else     STAGE(kdst1, vdst1, cc + 1);
        }
        const ushort* sk = stgK[buf];
        const ushort* sv = stgV[buf];

        // ---- swapped one-parity QK^T: C = S^T, exp2 + pack in-register ----
        union { f16x8 w8; f16x4 q[2]; } pw;
#pragma unroll
        for (int sb = 0; sb < 2; ++sb) {
            const int rb = (sb * 16 + col) * 64;
            f16x8 ka0 = ld8(&sk[p * 2048 + rb + kx]);
            f16x8 ka1 = ld8(&sk[p * 2048 + rb + kx2]);
            f16x8 kb0 = ld8(&sk[(p ^ 1) * 2048 + rb + kx]);
            f16x8 kb1 = ld8(&sk[(p ^ 1) * 2048 + rb + kx2]);
            f32x4 a0 = (f32x4){0.f, 0.f, 0.f, 0.f};
            a0 = MFMA(ka0, qr0, a0); a0 = MFMA(ka1, qr1, a0);
            a0 = MFMA(kb0, qx0, a0); a0 = MFMA(kb1, qx1, a0);
            const float w0 = EXP2(a0[0]), w1 = EXP2(a0[1]);
            const float w2 = EXP2(a0[2]), w3 = EXP2(a0[3]);
            dsum += (w0 + w1) + (w2 + w3);
            pw.q[sb] = pack4(w0, w1, w2, w3);
        }

        // ---- PV: one b128 + one MFMA32 per (db, part) ----
        __builtin_amdgcn_s_setprio(1);
#pragma unroll
        for (int db = 0; db < 4; ++db) {
            const int rv = (db * 16 + col) * 64;
            uA[db] = MFMA(pw.w8, ld8(&sv[rv + vxA]), uA[db]);
            uB[db] = MFMA(pw.w8, ld8(&sv[rv + vxB]), uB[db]);
        }
        __builtin_amdgcn_s_setprio(0);

        __syncthreads();   // staged buf^1 complete (vmcnt0) + all done with buf
    }

    // ---- denominator: lane holds partial for l=col; reduce over g-lanes ----
    dsum += __shfl_xor(dsum, 16);
    dsum += __shfl_xor(dsum, 32);
    const float rd = 1.f / dsum;
    if (lane < 16) rdbuf[p * 32768 + nh * 1024 + l0 + col] = rd;

    // u rows are l=4g+r -> fetch rd from lane 4g+r
    float rdl[4];
#pragma unroll
    for (int r = 0; r < 4; ++r) rdl[r] = __shfl(rd, 4 * g + r);

#pragma unroll
    for (int db = 0; db < 4; ++db) {
#pragma unroll
        for (int r = 0; r < 4; ++r) {
            uA[db][r] *= rdl[r];
            uB[db][r] *= rdl[r];
        }
    }

    // ---- exchange via dead stgK (16KB): [lsub][lane][16 f32] contiguous ----
    float* cb = (float*)&stgK[0][0];
    const int ci = (lsub * 64 + lane) * 16;
    if (p == 1) {
#pragma unroll
        for (int db = 0; db < 4; ++db) *(f32x4*)&cb[ci + db * 4] = uB[db];
    }
    __syncthreads();
    f32x4 oR[4];
    if (p == 0) {
#pragma unroll
        for (int db = 0; db < 4; ++db) oR[db] = uA[db] - *(f32x4*)&cb[ci + db * 4];
    }
    __syncthreads();
    if (p == 1) {
#pragma unroll
        for (int db = 0; db < 4; ++db) *(f32x4*)&cb[ci + db * 4] = uA[db];
    }
    __syncthreads();

    if (p == 0) {
        const long OFF_UI = 2097152;
#pragma unroll
        for (int db = 0; db < 4; ++db) {
            f32x4 oI = uB[db] + *(f32x4*)&cb[ci + db * 4];
#pragma unroll
            for (int r = 0; r < 4; ++r) {
                const int l = l0 + 4 * g + r;
                const int d = db * 16 + col;
                const long base = (((long)n * L_ + l) * H_ + h) * D_ + d;
                out[base] = oR[db][r];
                out[OFF_UI + base] = oI[r];
            }
        }
    }
#undef STAGE
}

// ---- a = 0.125 * sum_h exp2(arg_h) * rd_h ---- LDS-staged K recompute
// grid 1024 (XCD-swizzled -> (n, l-tile64, s-chunk64)), block 256 = 4 waves,
// wave owns 16 l-rows x full 64-s chunk. h-loop with double-buffered LDS K
// staging (global_load_lds, both-sides XOR swizzle), in-register h-sum.
__launch_bounds__(256, 4)
__global__ void kern_a(const float* __restrict__ qr_g, const float* __restrict__ qi_g,
                      const ushort* __restrict__ ws, const float* __restrict__ rdbuf,
                      float* __restrict__ out) {
    __shared__ ushort stgK[2][2][64][64];   // [buf][part][s][d]  32KB
    __shared__ float lrd[8][2][64];         // [h][part][row]      4KB

    const int tid  = threadIdx.x;
    const int lane = tid & 63;
    const int wv   = tid >> 6;
    const int col  = lane & 15;
    const int g    = lane >> 4;

    // XCD swizzle: id&7 = XCD x; n = x>>1 -> K(n)=4MB resident per L2 pair
    const int id  = blockIdx.x;
    const int x   = id & 7;
    const int q   = id >> 3;             // 0..127
    const int n   = x >> 1;
    const int idx = (x & 1) * 128 + q;   // 0..255 within n
    const int lt0 = (idx >> 4) * 64;     // l-tile base
    const int sc  = idx & 15;            // s-chunk (64 cols)
    const int l0  = lt0 + wv * 16;       // wave's row base

    const ushort* KrB = ws + ((long)(n * 8) << 16);             // head 0
    const ushort* KiB = ws + (1l << 21) + ((long)(n * 8) << 16);

    // preload rd for all 8 heads x 64 rows
#pragma unroll
    for (int i = 0; i < 4; ++i) {
        const int t = i * 256 + tid;
        (&lrd[0][0][0])[t] =
            rdbuf[((t >> 6) & 1) * 32768 + (n * 8 + (t >> 7)) * 1024 + lt0 + (t & 63)];
    }

    // staging roles: wave stages part sp, rows (wv&1)*32 .. +32
    const int sp   = wv >> 1;
    const int kbs  = ((lane & 7) ^ (lane >> 3)) * 8;   // pre-swizzled src block

#define STAGEA(buf, hh)                                                      \
    do {                                                                     \
        const ushort* Kp = (sp ? KiB : KrB) + ((long)(hh) << 16);            \
        _Pragma("unroll")                                                    \
        for (int i = 0; i < 4; ++i) {                                        \
            const int krow = (wv & 1) * 32 + i * 8 + (lane >> 3);            \
            gl_lds16(Kp + (long)(sc * 64 + krow) * 64 + kbs,                 \
                     &stgK[buf][sp][(wv & 1) * 32 + i * 8][0]);              \
        }                                                                    \
    } while (0)

    f32x4 aR[4], aI[4];
#pragma unroll
    for (int i = 0; i < 4; ++i) {
        aR[i] = (f32x4){0.f, 0.f, 0.f, 0.f};
        aI[i] = (f32x4){0.f, 0.f, 0.f, 0.f};
    }

    const int kx  = (g ^ (col & 7)) * 8;
    const int kx2 = ((g + 4) ^ (col & 7)) * 8;

    STAGEA(0, 0);
    __syncthreads();

    for (int h = 0; h < 8; ++h) {
        const int buf = h & 1;
        if (h < 7) STAGEA(buf ^ 1, h + 1);

        // Q fragments for this head (row = col of wave's 16, k = g*8+e)
        const long qg = (((long)n * 1024 + l0 + col) * 8 + h) * 64 + g * 8;
        const f16x8 qr0 = cvt8(qr_g + qg), qr1 = cvt8(qr_g + qg + 32);
        const f16x8 qi0 = cvt8(qi_g + qg), qi1 = cvt8(qi_g + qg + 32);
        const f16x8 qn0 = negf(qi0), qn1 = negf(qi1);

        float rdR[4], rdI[4];
#pragma unroll
        for (int r = 0; r < 4; ++r) {
            rdR[r] = lrd[h][0][wv * 16 + 4 * g + r];
            rdI[r] = lrd[h][1][wv * 16 + 4 * g + r];
        }

#pragma unroll
        for (int sb = 0; sb < 4; ++sb) {
            const int row = sb * 16 + col;
            f16x8 kr0 = ld8(&stgK[buf][0][row][kx]);
            f16x8 kr1 = ld8(&stgK[buf][0][row][kx2]);
            f16x8 ki0 = ld8(&stgK[buf][1][row][kx]);
            f16x8 ki1 = ld8(&stgK[buf][1][row][kx2]);
            f32x4 a0 = (f32x4){0.f, 0.f, 0.f, 0.f};
            a0 = MFMA(qr0, kr0, a0); a0 = MFMA(qr1, kr1, a0);
            a0 = MFMA(qn0, ki0, a0); a0 = MFMA(qn1, ki1, a0);
            f32x4 a1 = (f32x4){0.f, 0.f, 0.f, 0.f};
            a1 = MFMA(qr0, ki0, a1); a1 = MFMA(qr1, ki1, a1);
            a1 = MFMA(qi0, kr0, a1); a1 = MFMA(qi1, kr1, a1);
#pragma unroll
            for (int r = 0; r < 4; ++r) {
                aR[sb][r] += EXP2(a0[r]) * rdR[r];
                aI[sb][r] += EXP2(a1[r]) * rdI[r];
            }
        }
        __syncthreads();
    }

    const long OFF_AR = 4194304;
    const long OFF_AI = 8388608;
#pragma unroll
    for (int sb = 0; sb < 4; ++sb) {
#pragma unroll
        for (int r = 0; r < 4; ++r) {
            const int l = l0 + 4 * g + r;
            const int s = sc * 64 + sb * 16 + col;
            const long ab = ((long)n * 1024 + l) * 1024 + s;
            out[OFF_AR + ab] = aR[sb][r] * 0.125f;
            out[OFF_AI + ab] = aI[sb][r] * 0.125f;
        }
    }
#undef STAGEA
}

extern "C" void kernel_launch(void* const* d_in, const int* in_sizes, int n_in,
                              void* d_out, int out_size, void* d_ws, size_t ws_size,
                              hipStream_t stream) {
    const float* qr = (const float*)d_in[0];
    const float* qi = (const float*)d_in[1];
    const float* kr = (const float*)d_in[2];
    const float* ki = (const float*)d_in[3];
    const float* vr = (const float*)d_in[4];
    const float* vi = (const float*)d_in[5];
    ushort* ws = (ushort*)d_ws;                              // 16 MB f16 K/V
    float* rdbuf = (float*)((char*)d_ws + (16ull << 20));    // 256 KB @ 16 MB
    float* out = (float*)d_out;

    hipLaunchKernelGGL(cvt_kv, dim3(5120), dim3(256), 0, stream, kr, ki, vr, vi, ws);
    hipLaunchKernelGGL(attn_u, dim3(512), dim3(512), 0, stream, qr, qi, ws, rdbuf, out);
    hipLaunchKernelGGL(kern_a, dim3(1024), dim3(256), 0, stream, qr, qi, ws, rdbuf, out);
}